// Round 3
// baseline (436.610 us; speedup 1.0000x reference)
//
#include <hip/hip_runtime.h>
#include <hip/hip_bf16.h>

typedef __attribute__((ext_vector_type(8))) __bf16 bf16x8;
typedef __attribute__((ext_vector_type(4))) float f32x4;

#define BATCH 16
#define LSEQ 2048
#define DIM 128
#define EPITCH 2056   // bf16 elems per LDS row: 2048 + 8 pad

__device__ __forceinline__ bf16x8 cvt8(float4 a, float4 b) {
    bf16x8 r;
    r[0] = (__bf16)a.x; r[1] = (__bf16)a.y; r[2] = (__bf16)a.z; r[3] = (__bf16)a.w;
    r[4] = (__bf16)b.x; r[5] = (__bf16)b.y; r[6] = (__bf16)b.z; r[7] = (__bf16)b.w;
    return r;
}

// ---------------- preproc: K -> bf16 (same layout) ----------------
__global__ __launch_bounds__(256)
void cast_k_kernel(const float* __restrict__ in, __bf16* __restrict__ out) {
    size_t i = ((size_t)blockIdx.x * 256 + threadIdx.x) * 8;
    const float4* p = reinterpret_cast<const float4*>(in + i);
    *reinterpret_cast<bf16x8*>(out + i) = cvt8(p[0], p[1]);
}

// ---------------- preproc: V -> bf16 transposed Vt[b][d][k] ----------------
__global__ __launch_bounds__(256)
void transpose_v_kernel(const float* __restrict__ v, __bf16* __restrict__ vt) {
    __shared__ __bf16 t[32][DIM + 8];
    const int b = blockIdx.y, k0 = blockIdx.x * 32;
    const int tid = threadIdx.x;
    {
        const int r = tid >> 3, c8 = tid & 7;
        const float* src = v + ((size_t)b * LSEQ + k0 + r) * DIM;
        #pragma unroll
        for (int j = 0; j < 4; ++j) {
            const int c = (c8 + 8 * j) * 4;
            float4 x = *reinterpret_cast<const float4*>(src + c);
            t[r][c + 0] = (__bf16)x.x; t[r][c + 1] = (__bf16)x.y;
            t[r][c + 2] = (__bf16)x.z; t[r][c + 3] = (__bf16)x.w;
        }
    }
    __syncthreads();
    {
        const int d = tid >> 1, ho = (tid & 1) * 16;
        __bf16* dst = vt + ((size_t)b * DIM + d) * LSEQ + k0 + ho;
        bf16x8 w0, w1;
        #pragma unroll
        for (int j = 0; j < 8; ++j) { w0[j] = t[ho + j][d]; w1[j] = t[ho + 8 + j][d]; }
        *reinterpret_cast<bf16x8*>(dst) = w0;
        *reinterpret_cast<bf16x8*>(dst + 8) = w1;
    }
}

// ---------------- preproc: mask -> fragment-order bit pack ----------------
// maskpk[b][qt][wave][it][lane] : byte bit (t*4+r) =
//   mask[b][qt*16 + g*4 + r][wave*512 + it*32 + t*16 + li]   (lane = g*16+li)
__global__ __launch_bounds__(256)
void pack_mask_kernel(const int* __restrict__ maskg, unsigned char* __restrict__ mp) {
    const int tid  = threadIdx.x;
    const int wv   = tid >> 6;
    const int lane = tid & 63;
    const int g    = lane >> 4;
    const int li   = lane & 15;
    const int qt   = blockIdx.x;
    const int b    = blockIdx.y;

    const int* mbase = maskg + ((size_t)b * LSEQ + qt * 16) * LSEQ + wv * 512 + li;
    unsigned char* out = mp + ((((size_t)b * 128 + qt) * 4 + wv) * 16) * 64 + lane;

    #pragma unroll
    for (int it = 0; it < 16; ++it) {
        unsigned byte = 0;
        #pragma unroll
        for (int t = 0; t < 2; ++t)
            #pragma unroll
            for (int r = 0; r < 4; ++r) {
                int m = mbase[(size_t)(g * 4 + r) * LSEQ + it * 32 + t * 16];
                byte |= (m ? 1u : 0u) << (t * 4 + r);
            }
        out[(size_t)it * 64] = (unsigned char)byte;
    }
}

__device__ __forceinline__ void load_k_pre(const __bf16* __restrict__ kbf, size_t browbase,
                                           int kb, int li, int g, bf16x8* kf) {
    const __bf16* p0 = kbf + (browbase + kb + li) * DIM + g * 8;
    #pragma unroll
    for (int t = 0; t < 2; ++t)
        #pragma unroll
        for (int d = 0; d < 4; ++d)
            kf[t * 4 + d] = *reinterpret_cast<const bf16x8*>(p0 + (size_t)t * 16 * DIM + d * 32);
}

// ========================= fused main (PRE path) =========================
__global__ __launch_bounds__(256, 2)
void sdpa_fused_pre(const float* __restrict__ qg,
                    const __bf16* __restrict__ kbf,
                    const __bf16* __restrict__ vtb,
                    const unsigned char* __restrict__ mpk,
                    float* __restrict__ og,
                    float* __restrict__ wg)
{
    __shared__ __align__(16) __bf16 Es[16 * EPITCH];
    __shared__ float Osum[16 * DIM];
    __shared__ float rowpart[4][16];
    __shared__ float rowinv[16];

    const int tid  = threadIdx.x;
    const int wave = tid >> 6;
    const int lane = tid & 63;
    const int g    = lane >> 4;
    const int li   = lane & 15;

    const int qt = blockIdx.x;
    const int b  = blockIdx.y;
    const int q0 = qt * 16;

    for (int i = tid; i < 16 * DIM; i += 256) Osum[i] = 0.0f;

    const float qscale = 0.08838834764831845f * 1.4426950408889634f; // 1/sqrt(128)*log2e
    bf16x8 qf[4];
    {
        const float* qrow = qg + ((size_t)b * LSEQ + q0 + li) * DIM + g * 8;
        #pragma unroll
        for (int d = 0; d < 4; ++d) {
            const float4* p4 = reinterpret_cast<const float4*>(qrow + d * 32);
            float4 x = p4[0];
            float4 y = p4[1];
            x.x *= qscale; x.y *= qscale; x.z *= qscale; x.w *= qscale;
            y.x *= qscale; y.y *= qscale; y.z *= qscale; y.w *= qscale;
            qf[d] = cvt8(x, y);
        }
    }

    float rsum[4] = {0.f, 0.f, 0.f, 0.f};
    f32x4 accO[8];
    #pragma unroll
    for (int i = 0; i < 8; ++i) accO[i] = (f32x4){0.f, 0.f, 0.f, 0.f};

    const int kwave0 = wave * 512;
    const size_t browbase = (size_t)b * LSEQ;
    const __bf16* vbase = vtb + ((size_t)b * DIM + li) * LSEQ + g * 8;
    const unsigned char* mpb = mpk + ((((size_t)b * 128 + qt) * 4 + wave) * 16) * 64 + lane;

    // pipeline state: K 1-deep, V 1-deep (double buffer), mask bytes 2-deep
    bf16x8 kc[8], vcA[8], vcB[8];
    unsigned mc, mn;

    load_k_pre(kbf, browbase, kwave0, li, g, kc);
    #pragma unroll
    for (int dt = 0; dt < 8; ++dt)
        vcA[dt] = *reinterpret_cast<const bf16x8*>(vbase + kwave0 + (size_t)dt * 16 * LSEQ);
    mc = mpb[0];
    mn = mpb[64];

    auto body = [&](int it, bf16x8* vcur, bf16x8* vnxt) {
        const int kb = kwave0 + it * 32;

        // ---- QK^T (kc prefetched)
        f32x4 s0 = (f32x4){0.f, 0.f, 0.f, 0.f};
        f32x4 s1 = (f32x4){0.f, 0.f, 0.f, 0.f};
        #pragma unroll
        for (int d = 0; d < 4; ++d) {
            s0 = __builtin_amdgcn_mfma_f32_16x16x32_bf16(qf[d], kc[d],     s0, 0, 0, 0);
            s1 = __builtin_amdgcn_mfma_f32_16x16x32_bf16(qf[d], kc[4 + d], s1, 0, 0, 0);
        }

        // ---- prefetch K and V for it+1 (clamped in-bounds on last iter)
        const int kbn = (it + 1 < 16) ? kb + 32 : kwave0;
        load_k_pre(kbf, browbase, kbn, li, g, kc);
        #pragma unroll
        for (int dt = 0; dt < 8; ++dt)
            vnxt[dt] = *reinterpret_cast<const bf16x8*>(vbase + kbn + (size_t)dt * 16 * LSEQ);

        // ---- mask bits + exp2 + E store + row sums
        const unsigned mb = mc;
        #pragma unroll
        for (int t = 0; t < 2; ++t) {
            f32x4 sv = t ? s1 : s0;
            const int col = kb + t * 16 + li;
            #pragma unroll
            for (int r = 0; r < 4; ++r) {
                float sc = ((mb >> (t * 4 + r)) & 1u) ? -1.0e9f : sv[r];
                float ev = __builtin_amdgcn_exp2f(sc);
                rsum[r] += ev;
                Es[(g * 4 + r) * EPITCH + col] = (__bf16)ev;
            }
        }
        mc = mn;
        {
            const int itn = (it + 2 < 16) ? it + 2 : 15;
            mn = mpb[(size_t)itn * 64];
        }

        // ---- PV with V prefetched a full iteration ago
        bf16x8 af = *reinterpret_cast<const bf16x8*>(&Es[li * EPITCH + kb + g * 8]);
        #pragma unroll
        for (int dt = 0; dt < 8; ++dt)
            accO[dt] = __builtin_amdgcn_mfma_f32_16x16x32_bf16(af, vcur[dt], accO[dt], 0, 0, 0);
    };

    for (int i2 = 0; i2 < 8; ++i2) {
        body(2 * i2,     vcA, vcB);
        body(2 * i2 + 1, vcB, vcA);
    }

    // ---- row-sum reduce across the 16 li lanes
    #pragma unroll
    for (int off = 1; off < 16; off <<= 1) {
        #pragma unroll
        for (int r = 0; r < 4; ++r) rsum[r] += __shfl_xor(rsum[r], off, 64);
    }
    if (li == 0) {
        #pragma unroll
        for (int r = 0; r < 4; ++r) rowpart[wave][g * 4 + r] = rsum[r];
    }
    __syncthreads();

    #pragma unroll
    for (int dt = 0; dt < 8; ++dt) {
        #pragma unroll
        for (int r = 0; r < 4; ++r)
            atomicAdd(&Osum[(g * 4 + r) * DIM + dt * 16 + li], accO[dt][r]);
    }
    if (tid < 16) {
        float s = rowpart[0][tid] + rowpart[1][tid] + rowpart[2][tid] + rowpart[3][tid];
        rowinv[tid] = 1.0f / s;
    }
    __syncthreads();

    // ---- write W = E * rowinv (b128 LDS reads, float4 stores)
    const size_t wbase = (browbase + q0) * LSEQ;
    for (int i = tid; i < 16 * (LSEQ / 8); i += 256) {
        const int row = i >> 8;
        const int col = (i & 255) * 8;
        bf16x8 e = *reinterpret_cast<const bf16x8*>(&Es[row * EPITCH + col]);
        const float inv = rowinv[row];
        float4 w0, w1;
        w0.x = (float)e[0] * inv; w0.y = (float)e[1] * inv;
        w0.z = (float)e[2] * inv; w0.w = (float)e[3] * inv;
        w1.x = (float)e[4] * inv; w1.y = (float)e[5] * inv;
        w1.z = (float)e[6] * inv; w1.w = (float)e[7] * inv;
        float* dst = wg + wbase + (size_t)row * LSEQ + col;
        *reinterpret_cast<float4*>(dst)     = w0;
        *reinterpret_cast<float4*>(dst + 4) = w1;
    }

    // ---- write O = Osum * rowinv
    const size_t obase = (browbase + q0) * DIM;
    for (int i = tid; i < 16 * DIM; i += 256) {
        const int row = i >> 7;
        og[obase + i] = Osum[i] * rowinv[row];
    }
}

// ========================= fallback (no workspace) =========================
__global__ __launch_bounds__(256, 2)
void sdpa_fused_plain(const float* __restrict__ qg,
                      const float* __restrict__ kg,
                      const float* __restrict__ vg,
                      const int*   __restrict__ maskg,
                      float* __restrict__ og,
                      float* __restrict__ wg)
{
    __shared__ __align__(16) __bf16 Es[16 * EPITCH];
    __shared__ float Osum[16 * DIM];
    __shared__ float rowpart[4][16];
    __shared__ float rowinv[16];

    const int tid  = threadIdx.x;
    const int wave = tid >> 6;
    const int lane = tid & 63;
    const int g    = lane >> 4;
    const int li   = lane & 15;
    const int qt = blockIdx.x;
    const int b  = blockIdx.y;
    const int q0 = qt * 16;

    for (int i = tid; i < 16 * DIM; i += 256) Osum[i] = 0.0f;

    const float qscale = 0.08838834764831845f * 1.4426950408889634f;
    bf16x8 qf[4];
    {
        const float* qrow = qg + ((size_t)b * LSEQ + q0 + li) * DIM + g * 8;
        #pragma unroll
        for (int d = 0; d < 4; ++d) {
            const float4* p4 = reinterpret_cast<const float4*>(qrow + d * 32);
            float4 x = p4[0];
            float4 y = p4[1];
            x.x *= qscale; x.y *= qscale; x.z *= qscale; x.w *= qscale;
            y.x *= qscale; y.y *= qscale; y.z *= qscale; y.w *= qscale;
            qf[d] = cvt8(x, y);
        }
    }

    float rsum[4] = {0.f, 0.f, 0.f, 0.f};
    f32x4 accO[8];
    #pragma unroll
    for (int i = 0; i < 8; ++i) accO[i] = (f32x4){0.f, 0.f, 0.f, 0.f};

    const int kwave0 = wave * 512;
    const size_t browbase = (size_t)b * LSEQ;

    for (int it = 0; it < 16; ++it) {
        const int kb = kwave0 + it * 32;
        f32x4 s0 = (f32x4){0.f, 0.f, 0.f, 0.f};
        f32x4 s1 = (f32x4){0.f, 0.f, 0.f, 0.f};
        {
            const float* kp0 = kg + (browbase + kb + li) * DIM + g * 8;
            const float* kp1 = kp0 + (size_t)16 * DIM;
            #pragma unroll
            for (int d = 0; d < 4; ++d) {
                const float4* a4 = reinterpret_cast<const float4*>(kp0 + d * 32);
                const float4* b4 = reinterpret_cast<const float4*>(kp1 + d * 32);
                s0 = __builtin_amdgcn_mfma_f32_16x16x32_bf16(qf[d], cvt8(a4[0], a4[1]), s0, 0, 0, 0);
                s1 = __builtin_amdgcn_mfma_f32_16x16x32_bf16(qf[d], cvt8(b4[0], b4[1]), s1, 0, 0, 0);
            }
        }
        const int* mbase = maskg + (browbase + q0) * LSEQ + kb + li;
        #pragma unroll
        for (int t = 0; t < 2; ++t) {
            f32x4 sv = t ? s1 : s0;
            const int col = kb + t * 16 + li;
            #pragma unroll
            for (int r = 0; r < 4; ++r) {
                const int m = mbase[(size_t)(g * 4 + r) * LSEQ + t * 16];
                float sc = m ? -1.0e9f : sv[r];
                float ev = __builtin_amdgcn_exp2f(sc);
                rsum[r] += ev;
                Es[(g * 4 + r) * EPITCH + col] = (__bf16)ev;
            }
        }
        bf16x8 af = *reinterpret_cast<const bf16x8*>(&Es[li * EPITCH + kb + g * 8]);
        const float* vb = vg + (browbase + kb + g * 8) * DIM + li;
        #pragma unroll
        for (int dt = 0; dt < 8; ++dt) {
            const float* vp = vb + dt * 16;
            bf16x8 bf;
            #pragma unroll
            for (int j = 0; j < 8; ++j) bf[j] = (__bf16)vp[(size_t)j * DIM];
            accO[dt] = __builtin_amdgcn_mfma_f32_16x16x32_bf16(af, bf, accO[dt], 0, 0, 0);
        }
    }

    #pragma unroll
    for (int off = 1; off < 16; off <<= 1) {
        #pragma unroll
        for (int r = 0; r < 4; ++r) rsum[r] += __shfl_xor(rsum[r], off, 64);
    }
    if (li == 0) {
        #pragma unroll
        for (int r = 0; r < 4; ++r) rowpart[wave][g * 4 + r] = rsum[r];
    }
    __syncthreads();
    #pragma unroll
    for (int dt = 0; dt < 8; ++dt) {
        #pragma unroll
        for (int r = 0; r < 4; ++r)
            atomicAdd(&Osum[(g * 4 + r) * DIM + dt * 16 + li], accO[dt][r]);
    }
    if (tid < 16) {
        float s = rowpart[0][tid] + rowpart[1][tid] + rowpart[2][tid] + rowpart[3][tid];
        rowinv[tid] = 1.0f / s;
    }
    __syncthreads();

    const size_t wbase = (browbase + q0) * LSEQ;
    for (int i = tid; i < 16 * (LSEQ / 8); i += 256) {
        const int row = i >> 8;
        const int col = (i & 255) * 8;
        bf16x8 e = *reinterpret_cast<const bf16x8*>(&Es[row * EPITCH + col]);
        const float inv = rowinv[row];
        float4 w0, w1;
        w0.x = (float)e[0] * inv; w0.y = (float)e[1] * inv;
        w0.z = (float)e[2] * inv; w0.w = (float)e[3] * inv;
        w1.x = (float)e[4] * inv; w1.y = (float)e[5] * inv;
        w1.z = (float)e[6] * inv; w1.w = (float)e[7] * inv;
        float* dst = wg + wbase + (size_t)row * LSEQ + col;
        *reinterpret_cast<float4*>(dst)     = w0;
        *reinterpret_cast<float4*>(dst + 4) = w1;
    }
    const size_t obase = (browbase + q0) * DIM;
    for (int i = tid; i < 16 * DIM; i += 256) {
        const int row = i >> 7;
        og[obase + i] = Osum[i] * rowinv[row];
    }
}

extern "C" void kernel_launch(void* const* d_in, const int* in_sizes, int n_in,
                              void* d_out, int out_size, void* d_ws, size_t ws_size,
                              hipStream_t stream) {
    const float* q    = (const float*)d_in[0];
    const float* k    = (const float*)d_in[1];
    const float* v    = (const float*)d_in[2];
    const int*   mask = (const int*)d_in[3];
    float* o = (float*)d_out;
    float* w = (float*)d_out + (size_t)BATCH * LSEQ * DIM;

    const size_t nKV    = (size_t)BATCH * LSEQ * DIM;                 // 4.19M elems
    const size_t mpSize = (size_t)BATCH * 128 * 4 * 16 * 64;          // 8 MB
    const size_t need   = 2 * nKV * sizeof(__bf16) + mpSize;          // 24 MB

    dim3 grid(LSEQ / 16, BATCH);
    if (ws_size >= need) {
        __bf16* kbf = (__bf16*)d_ws;
        __bf16* vt  = kbf + nKV;
        unsigned char* mp = (unsigned char*)(vt + nKV);
        cast_k_kernel<<<nKV / 2048, 256, 0, stream>>>(k, kbf);
        transpose_v_kernel<<<dim3(LSEQ / 32, BATCH), 256, 0, stream>>>(v, vt);
        pack_mask_kernel<<<dim3(128, BATCH), 256, 0, stream>>>(mask, mp);
        sdpa_fused_pre<<<grid, 256, 0, stream>>>(q, kbf, vt, mp, o, w);
    } else {
        sdpa_fused_plain<<<grid, 256, 0, stream>>>(q, k, v, mask, o, w);
    }
}